// Round 13
// baseline (686.395 us; speedup 1.0000x reference)
//
#include <hip/hip_runtime.h>
#include <hip/hip_bf16.h>

typedef unsigned short u16;
typedef __attribute__((ext_vector_type(8))) short bf16x8;
typedef __attribute__((ext_vector_type(4))) float f32x4;
typedef __attribute__((ext_vector_type(16))) float f32x16;

#define QSCALE 0.180336880f   // 0.125 * log2(e): softmax computed in exp2 domain

#define DEV static __device__ __forceinline__

DEV u16 f2bf(float f) {
  union { float f; unsigned u; } v; v.f = f;
  unsigned r = v.u + 0x7fffu + ((v.u >> 16) & 1u);  // round-to-nearest-even
  return (u16)(r >> 16);
}

DEV unsigned pk2(float a, float b) {   // two f32 -> packed bf16x2 (RNE), low = a
  union { __hip_bfloat162 h; unsigned u; } c;
  c.h = __float22bfloat162_rn(make_float2(a, b));
  return c.u;
}

DEV void gll16(void* lds, const void* g) {
  __builtin_amdgcn_global_load_lds(
      (const __attribute__((address_space(1))) unsigned int*)g,
      (__attribute__((address_space(3))) unsigned int*)lds, 16, 0, 0);
}

// ---------------- pack: fp32 -> bf16 ----------------
__global__ __launch_bounds__(256) void cvt_f32_to_bf16(const float* __restrict__ in,
                                                       u16* __restrict__ out, int n4) {
  int i = blockIdx.x * blockDim.x + threadIdx.x;
  int stride = gridDim.x * blockDim.x;
  for (; i < n4; i += stride) {
    float4 f = ((const float4*)in)[i];
    ushort4 u;
    u.x = f2bf(f.x); u.y = f2bf(f.y); u.z = f2bf(f.z); u.w = f2bf(f.w);
    ((ushort4*)out)[i] = u;
  }
}

// ---------------- pack: W[K][N] fp32 -> Wt[N][K] bf16, cols < sn scaled ----------------
__global__ __launch_bounds__(256) void transpose_cvt(const float* __restrict__ W,
                                                     u16* __restrict__ Wt,
                                                     int K, int N, int sn, float sval) {
  __shared__ u16 t[64][65];
  const int k0 = blockIdx.x * 64, n0 = blockIdx.y * 64;
  const int tid = threadIdx.x;
  const int rr = tid >> 4;        // 0..15
  const int cc = (tid & 15) * 4;  // 0..60
  const float scl = (n0 < sn) ? sval : 1.0f;
#pragma unroll
  for (int i = 0; i < 4; ++i) {
    const int row = rr * 4 + i;
    float4 f = *(const float4*)&W[(size_t)(k0 + row) * N + n0 + cc];
    t[row][cc + 0] = f2bf(f.x * scl);
    t[row][cc + 1] = f2bf(f.y * scl);
    t[row][cc + 2] = f2bf(f.z * scl);
    t[row][cc + 3] = f2bf(f.w * scl);
  }
  __syncthreads();
#pragma unroll
  for (int i = 0; i < 4; ++i) {
    const int n = rr * 4 + i;
    ushort4 u;
    u.x = t[cc + 0][n]; u.y = t[cc + 1][n]; u.z = t[cc + 2][n]; u.w = t[cc + 3][n];
    *(ushort4*)&Wt[(size_t)(n0 + n) * K + k0 + cc] = u;
  }
}

// ---------------- transpose V part of qkv: -> vT[bh][d][t] ----------------
__global__ __launch_bounds__(256) void transpose_v(const u16* __restrict__ qkv,
                                                   u16* __restrict__ vT) {
  __shared__ u16 t[64][72];
  const int bh = blockIdx.y;          // b*16+h
  const int b = bh >> 4, h = bh & 15;
  const int t0 = blockIdx.x * 64;
  const int tid = threadIdx.x;
  const int row = tid >> 2;           // token within tile, 0..63
  const int cg = (tid & 3) * 16;      // d group
  const size_t src = (size_t)b * 2048 * 3072 + (size_t)(t0 + row) * 3072 + 2048 + h * 64 + cg;
  bf16x8 v0 = *(const bf16x8*)&qkv[src];
  bf16x8 v1 = *(const bf16x8*)&qkv[src + 8];
#pragma unroll
  for (int i = 0; i < 8; ++i) { t[row][cg + i] = (u16)v0[i]; t[row][cg + 8 + i] = (u16)v1[i]; }
  __syncthreads();
  const int d = tid >> 2;             // 0..63
  const int tg = (tid & 3) * 16;
  bf16x8 o0, o1;
#pragma unroll
  for (int i = 0; i < 8; ++i) { o0[i] = (short)t[tg + i][d]; o1[i] = (short)t[tg + 8 + i][d]; }
  u16* dst = &vT[((size_t)bh * 64 + d) * 2048 + t0 + tg];
  *(bf16x8*)dst = o0;
  *(bf16x8*)(dst + 8) = o1;
}

// ---------------- GEMM1: 256x256 tile, BK=32, 4-slot counted-vmcnt ring ------------
// (r12-verified: correct, ~4us gain over 128^2; kept unchanged)

#define G1_STAGE(S)                                                   \
  {                                                                   \
    gll16((u16*)L1[S] + wave * 512, g0); g0 += 32;                    \
    gll16((u16*)L1[S] + 4096 + wave * 512, g1); g1 += 32;             \
    gll16((u16*)L1[S] + 8192 + wave * 512, g2); g2 += 32;             \
    gll16((u16*)L1[S] + 12288 + wave * 512, g3); g3 += 32;            \
  }

#define G1_BODY(S, ISSUE, VM)                                         \
  {                                                                   \
    if (ISSUE) G1_STAGE((S + 2) & 3)                                  \
    asm volatile("s_waitcnt vmcnt(" #VM ")" ::: "memory");            \
    __builtin_amdgcn_s_barrier();                                     \
    const char* sb = (const char*)L1[S];                              \
    bf16x8 af[8], bfr[4];                                             \
    _Pragma("unroll")                                                 \
    for (int m = 0; m < 8; ++m) af[m] = *(const bf16x8*)(sb + aoff[m]); \
    _Pragma("unroll")                                                 \
    for (int n = 0; n < 4; ++n) bfr[n] = *(const bf16x8*)(sb + boff[n]); \
    __builtin_amdgcn_s_setprio(1);                                    \
    _Pragma("unroll")                                                 \
    for (int m = 0; m < 8; ++m)                                       \
      _Pragma("unroll")                                               \
      for (int n = 0; n < 4; ++n)                                     \
        acc[m][n] = __builtin_amdgcn_mfma_f32_16x16x32_bf16(af[m], bfr[n], acc[m][n], 0, 0, 0); \
    __builtin_amdgcn_s_setprio(0);                                    \
  }

__global__ __launch_bounds__(512, 2) void gemm1_256(const u16* __restrict__ A,
                                                    const u16* __restrict__ Bt,
                                                    const float* __restrict__ bias,
                                                    u16* __restrict__ C) {
  __shared__ __align__(16) u16 L1[4][16384];   // 4 slots x 32KB = 128KB
  const int tid = threadIdx.x;
  const int wave = tid >> 6, lane = tid & 63;
  const int g = lane >> 4, lr = lane & 15;
  const int wr = wave >> 2, wc = wave & 3;     // 2M x 4N wave grid
  const int id = blockIdx.x;                   // 384 blocks
  const int xcd = id & 7, j = id >> 3;         // j in 0..47
  const int bm = (xcd * 4 + (j & 3)) * 256;
  const int bn = (j >> 2) * 256;

  int aoff[8], boff[4];
#pragma unroll
  for (int m = 0; m < 8; ++m)
    aoff[m] = wr * 8192 + m * 1024 + g * 256 + lr * 16;
#pragma unroll
  for (int n = 0; n < 4; ++n)
    boff[n] = 16384 + wc * 4096 + n * 1024 + g * 256 + lr * 16;

  const u16* g0; const u16* g1; const u16* g2; const u16* g3;
  {
    const int b0 = wave * 1024 + lane * 16;
    const int plane = b0 >> 8, lrr = (b0 >> 4) & 15, pb = b0 & 15;
    const int row = (plane >> 2) * 16 + lrr;
    const int kc = (plane & 3) * 8 + (pb >> 1);
    g0 = A  + (size_t)(bm + row) * 1024 + kc;
    g1 = A  + (size_t)(bm + 128 + row) * 1024 + kc;
    g2 = Bt + (size_t)(bn + row) * 1024 + kc;
    g3 = Bt + (size_t)(bn + 128 + row) * 1024 + kc;
  }

  f32x4 acc[8][4] = {};

  G1_STAGE(0)
  G1_STAGE(1)

  for (int it = 0; it < 7; ++it) {
    G1_BODY(0, 1, 8) G1_BODY(1, 1, 8) G1_BODY(2, 1, 8) G1_BODY(3, 1, 8)
  }
  G1_BODY(0, 1, 8)
  G1_BODY(1, 1, 8)
  G1_BODY(2, 0, 4)
  G1_BODY(3, 0, 0)

#pragma unroll
  for (int m = 0; m < 8; ++m) {
#pragma unroll
    for (int n = 0; n < 4; ++n) {
      const int col = bn + wc * 64 + n * 16 + lr;
      float bv = bias[col];
      if (col < 1024) bv *= QSCALE;
#pragma unroll
      for (int r = 0; r < 4; ++r) {
        const int row = bm + wr * 128 + m * 16 + g * 4 + r;
        C[(size_t)row * 3072 + col] = f2bf(acc[m][n][r] + bv);
      }
    }
  }
}

// ---------------- bf16 GEMM (gemm2): 128x128 tile, m97 structure ----------------
template<bool OUT_BF16>
__global__ __launch_bounds__(256) void gemm_bf16(const u16* __restrict__ A,
                                                 const u16* __restrict__ Bt,
                                                 const float* __restrict__ bias,
                                                 void* __restrict__ Cout,
                                                 int M, int N, int K, int qn) {
  __shared__ __align__(16) u16 As[128][64];
  __shared__ __align__(16) u16 Bs[128][64];
  const int tid = threadIdx.x;
  const int wave = tid >> 6, lane = tid & 63;
  const int g = lane >> 4, lr = lane & 15;
  const int lid = blockIdx.y * gridDim.x + blockIdx.x;
  const int chunk = gridDim.x >> 3;
  const int xcd = lid & 7, j = lid >> 3;
  const int bm = (xcd * chunk + (j % chunk)) * 128;
  const int bn = (j / chunk) * 128;
  const int wm = (wave >> 1) * 64, wn = (wave & 1) * 64;
  f32x4 acc[4][4] = {};
  for (int kt = 0; kt < K; kt += 64) {
    __syncthreads();
#pragma unroll
    for (int jj = 0; jj < 4; ++jj) {
      int chnk = wave * 4 + jj;
      int e = chnk * 512 + lane * 8;
      int r = e >> 6, c = e & 63;
      gll16((u16*)As + chnk * 512, &A[(size_t)(bm + r) * K + kt + c]);
      gll16((u16*)Bs + chnk * 512, &Bt[(size_t)(bn + r) * K + kt + c]);
    }
    __syncthreads();
#pragma unroll
    for (int kk = 0; kk < 64; kk += 32) {
      bf16x8 af[4], bfr[4];
#pragma unroll
      for (int m = 0; m < 4; ++m)
        af[m] = *(const bf16x8*)&As[wm + m * 16 + lr][kk + g * 8];
#pragma unroll
      for (int n = 0; n < 4; ++n)
        bfr[n] = *(const bf16x8*)&Bs[wn + n * 16 + lr][kk + g * 8];
#pragma unroll
      for (int m = 0; m < 4; ++m)
#pragma unroll
        for (int n = 0; n < 4; ++n)
          acc[m][n] = __builtin_amdgcn_mfma_f32_16x16x32_bf16(af[m], bfr[n], acc[m][n], 0, 0, 0);
    }
  }
#pragma unroll
  for (int m = 0; m < 4; ++m) {
#pragma unroll
    for (int n = 0; n < 4; ++n) {
      const int col = bn + wn + n * 16 + lr;
      float bv = bias ? bias[col] : 0.f;
      if (col < qn) bv *= QSCALE;
#pragma unroll
      for (int r = 0; r < 4; ++r) {
        const int row = bm + wm + m * 16 + g * 4 + r;
        float v = acc[m][n][r] + bv;
        if (OUT_BF16) ((u16*)Cout)[(size_t)row * N + col] = f2bf(v);
        else          ((float*)Cout)[(size_t)row * N + col] = v;
      }
    }
  }
}

// ---------------- flash attention: intra-block split-K, 8 waves, LDS merge ---------
// 1-D grid 1024 x 512 threads (4 blocks/CU, 32 waves/CU = max occupancy).
// bh = ((id>>3)&7)*8 + (id&7) (XCD affinity); qt = id>>6.
// Waves 0-3 (group A): keys 0..1023. Waves 4-7 (group B): keys 1024..2047. Same
// 128 q-rows. Each group = r9 body (32x32 MFMA, swapped QK, in-reg P via
// cvt_pk+permlane32_swap, static-max softmax, plane LDS, 0 conflicts) on a private
// 16KB 2-slot end-drain pipeline (r6-verified sync: stage(t+1) at body start;
// vmcnt(0)+s_barrier at body end -- the wait covers loads issued a full body ago).
// Static-max makes the split-K merge exact: o = oA + oB, l = lA + lB (no rescale).
// B writes o/lsum to LDS (33KB total incl. pipeline area, conflict-free f32x4
// layout); one __syncthreads; A adds chunk-wise (f32x4 transients) and stores.

#define ATTN_BODY(S, ISSUE)                                                       \
  {                                                                               \
    if (ISSUE) {                                                                  \
      gll16(Kb + ((S) ^ 1) * 2048 + w4 * 512, gk); gk += 32 * 3072;               \
      gll16(Vb + ((S) ^ 1) * 2048 + w4 * 512, gv); gv += 32;                      \
    }                                                                             \
    const char* kb = (const char*)(Kb + (S) * 2048);                              \
    const char* vb = (const char*)(Vb + (S) * 2048);                              \
    f32x16 s = {};                                                                \
    __builtin_amdgcn_s_setprio(1);                                                \
    _Pragma("unroll")                                                             \
    for (int kk = 0; kk < 4; ++kk) {                                              \
      bf16x8 kf = *(const bf16x8*)(kb + koff[kk]);                                \
      s = __builtin_amdgcn_mfma_f32_32x32x16_bf16(kf, qf[kk], s, 0, 0, 0);        \
    }                                                                             \
    __builtin_amdgcn_s_setprio(0);                                                \
    float pr[16];                                                                 \
    _Pragma("unroll")                                                             \
    for (int r = 0; r < 16; ++r) pr[r] = __builtin_amdgcn_exp2f(s[r]);            \
    lsum += ((pr[0] + pr[1]) + (pr[2] + pr[3])) + ((pr[4] + pr[5]) + (pr[6] + pr[7])) \
          + ((pr[8] + pr[9]) + (pr[10] + pr[11])) + ((pr[12] + pr[13]) + (pr[14] + pr[15])); \
    union { unsigned u[4]; bf16x8 v; } pa0, pa1;                                  \
    {                                                                             \
      unsigned X0 = pk2(pr[0], pr[1]), X1 = pk2(pr[2], pr[3]);                    \
      unsigned Y0 = pk2(pr[4], pr[5]), Y1 = pk2(pr[6], pr[7]);                    \
      asm volatile("v_permlane32_swap_b32 %0, %1" : "+v"(X0), "+v"(Y0));          \
      asm volatile("v_permlane32_swap_b32 %0, %1" : "+v"(X1), "+v"(Y1));          \
      pa0.u[0] = X0; pa0.u[1] = X1; pa0.u[2] = Y0; pa0.u[3] = Y1;                 \
      unsigned Z0 = pk2(pr[8], pr[9]), Z1 = pk2(pr[10], pr[11]);                  \
      unsigned W0 = pk2(pr[12], pr[13]), W1 = pk2(pr[14], pr[15]);                \
      asm volatile("v_permlane32_swap_b32 %0, %1" : "+v"(Z0), "+v"(W0));          \
      asm volatile("v_permlane32_swap_b32 %0, %1" : "+v"(Z1), "+v"(W1));          \
      pa1.u[0] = Z0; pa1.u[1] = Z1; pa1.u[2] = W0; pa1.u[3] = W1;                 \
    }                                                                             \
    __builtin_amdgcn_s_setprio(1);                                                \
    {                                                                             \
      bf16x8 vf00 = *(const bf16x8*)(vb + voff[0][0]);                            \
      bf16x8 vf10 = *(const bf16x8*)(vb + voff[1][0]);                            \
      o0 = __builtin_amdgcn_mfma_f32_32x32x16_bf16(pa0.v, vf00, o0, 0, 0, 0);     \
      o1 = __builtin_amdgcn_mfma_f32_32x32x16_bf16(pa0.v, vf10, o1, 0, 0, 0);     \
      bf16x8 vf01 = *(const bf16x8*)(vb + voff[0][1]);                            \
      bf16x8 vf11 = *(const bf16x8*)(vb + voff[1][1]);                            \
      o0 = __builtin_amdgcn_mfma_f32_32x32x16_bf16(pa1.v, vf01, o0, 0, 0, 0);     \
      o1 = __builtin_amdgcn_mfma_f32_32x32x16_bf16(pa1.v, vf11, o1, 0, 0, 0);     \
    }                                                                             \
    __builtin_amdgcn_s_setprio(0);                                                \
    asm volatile("s_waitcnt vmcnt(0)" ::: "memory");                              \
    __builtin_amdgcn_s_barrier();                                                 \
  }

__global__ __launch_bounds__(512, 8) void attn_kernel(const u16* __restrict__ qkv,
                                                      const u16* __restrict__ vT,
                                                      u16* __restrict__ out) {
  __shared__ __align__(16) u16 lds[16896];   // 32KB pipeline (2 groups) + 1KB lsum
  const int tid = threadIdx.x;
  const int g8 = tid >> 6, lane = tid & 63;
  const int grp = g8 >> 2, w4 = g8 & 3;      // group (key half), wave-in-group
  const int hi = lane >> 5, l31 = lane & 31;
  const int id = blockIdx.x;
  const int bh = ((id >> 3) & 7) * 8 + (id & 7);   // XCD affinity: id%8 = bh%8
  const int b = bh >> 4, h = bh & 15;
  const int q0i = (id >> 6) * 128;
  const size_t base = (size_t)b * 2048 * 3072;
  const u16* kg = qkv + base + 1024 + h * 64;        // + t*3072 + d
  const u16* vg = vT + (size_t)bh * 64 * 2048;       // + d*2048 + t

  const int qrow = q0i + w4 * 32 + l31;
  bf16x8 qf[4];
#pragma unroll
  for (int kk = 0; kk < 4; ++kk)
    qf[kk] = *(const bf16x8*)&qkv[base + (size_t)qrow * 3072 + h * 64 + kk * 16 + hi * 8];

  int koff[4];
#pragma unroll
  for (int kk = 0; kk < 4; ++kk)
    koff[kk] = (kk * 2 + hi) * 512 + l31 * 16;
  int voff[2][2];
#pragma unroll
  for (int dt = 0; dt < 2; ++dt)
#pragma unroll
    for (int kp = 0; kp < 2; ++kp)
      voff[dt][kp] = (dt * 4 + kp * 2 + hi) * 512 + l31 * 16;

  u16* Kb = lds + grp * 8192;          // 2 slots x 2048 u16
  u16* Vb = lds + grp * 8192 + 4096;

  const u16* gk = kg + (size_t)(grp * 1024 + l31) * 3072 + w4 * 16 + hi * 8;
  const u16* gv = vg + (size_t)((w4 >> 1) * 32 + l31) * 2048 + grp * 1024
                + (w4 & 1) * 16 + hi * 8;

  f32x16 o0 = {}, o1 = {};
  float lsum = 0.f;

  // prologue: stage tile 0 into slot 0
  gll16(Kb + w4 * 512, gk); gk += 32 * 3072;
  gll16(Vb + w4 * 512, gv); gv += 32;
  asm volatile("s_waitcnt vmcnt(0)" ::: "memory");
  __builtin_amdgcn_s_barrier();

  for (int it = 0; it < 15; ++it) { ATTN_BODY(0, 1) ATTN_BODY(1, 1) }  // bodies 0..29
  ATTN_BODY(0, 1)    // body 30 (stages tile 31)
  ATTN_BODY(1, 0)    // body 31

  // ---- split-K merge: B -> LDS, A adds + normalizes + stores ----
  if (grp == 1) {
    char* ob = (char*)lds + w4 * 8192;
#pragma unroll
    for (int rq = 0; rq < 4; ++rq) {
      f32x4 u0 = { o0[rq * 4 + 0], o0[rq * 4 + 1], o0[rq * 4 + 2], o0[rq * 4 + 3] };
      f32x4 u1 = { o1[rq * 4 + 0], o1[rq * 4 + 1], o1[rq * 4 + 2], o1[rq * 4 + 3] };
      *(f32x4*)(ob + rq * 1024 + lane * 16) = u0;
      *(f32x4*)(ob + 4096 + rq * 1024 + lane * 16) = u1;
    }
    ((float*)((char*)lds + 32768))[w4 * 64 + lane] = lsum;
  }
  __syncthreads();
  if (grp == 0) {
    const float lB = ((const float*)((const char*)lds + 32768))[w4 * 64 + lane];
    const float ls = lsum + lB;
    const float lt = ls + __shfl_xor(ls, 32);
    const char* ob = (const char*)lds + w4 * 8192;
    const size_t orow0 = (size_t)b * 2048 + q0i + w4 * 32;
#pragma unroll
    for (int rq = 0; rq < 4; ++rq) {
      f32x4 u0 = *(const f32x4*)(ob + rq * 1024 + lane * 16);
      f32x4 u1 = *(const f32x4*)(ob + 4096 + rq * 1024 + lane * 16);
#pragma unroll
      for (int jj = 0; jj < 4; ++jj) {
        const int r = rq * 4 + jj;
        const int crow = jj + 8 * rq + 4 * hi;
        const float li = __shfl(lt, crow);
        u16* orow = out + (orow0 + crow) * 1024 + h * 64 + l31;
        orow[0]  = f2bf((o0[r] + u0[jj]) / li);
        orow[32] = f2bf((o1[r] + u1[jj]) / li);
      }
    }
  }
}

// ---------------- launcher ----------------
extern "C" void kernel_launch(void* const* d_in, const int* in_sizes, int n_in,
                              void* d_out, int out_size, void* d_ws, size_t ws_size,
                              hipStream_t stream) {
  (void)in_sizes; (void)n_in; (void)out_size; (void)ws_size;
  const float* x     = (const float*)d_in[0];  // [4,2048,1024]
  const float* w_in  = (const float*)d_in[1];  // [1024,3072]
  const float* b_in  = (const float*)d_in[2];  // [3072]
  const float* w_out = (const float*)d_in[3];  // [1024,1024]
  const float* b_out = (const float*)d_in[4];  // [1024]
  float* out = (float*)d_out;                  // [4,2048,1024] fp32

  char* ws = (char*)d_ws;
  u16* Xbf   = (u16*)ws; ws += (size_t)8192 * 1024 * 2;  // 16.8 MB (reused as vT)
  u16* WinT  = (u16*)ws; ws += (size_t)3072 * 1024 * 2;  //  6.3 MB
  u16* WoutT = (u16*)ws; ws += (size_t)1024 * 1024 * 2;  //  2.1 MB
  u16* qkv   = (u16*)ws; ws += (size_t)8192 * 3072 * 2;  // 50.3 MB
  u16* attno = (u16*)ws;                                  // 16.8 MB (total ~92.3 MB)
  u16* vT    = Xbf;   // alias: Xbf dead after gemm1; transpose_v runs after (stream-ordered)

  cvt_f32_to_bf16<<<2048, 256, 0, stream>>>(x, Xbf, 8192 * 1024 / 4);
  transpose_cvt<<<dim3(16, 48), 256, 0, stream>>>(w_in, WinT, 1024, 3072, 1024, QSCALE);
  transpose_cvt<<<dim3(16, 16), 256, 0, stream>>>(w_out, WoutT, 1024, 1024, 0, 1.0f);
  gemm1_256<<<384, 512, 0, stream>>>(Xbf, WinT, b_in, qkv);
  transpose_v<<<dim3(32, 64), 256, 0, stream>>>(qkv, vT);
  attn_kernel<<<1024, 512, 0, stream>>>(qkv, vT, attno);
  gemm_bf16<false><<<dim3(64, 8), 256, 0, stream>>>(attno, WoutT, b_out, out, 8192, 1024, 1024, 0);
}

// Round 14
// 224.367 us; speedup vs baseline: 3.0593x; 3.0593x over previous
//
#include <hip/hip_runtime.h>
#include <hip/hip_bf16.h>

typedef unsigned short u16;
typedef __attribute__((ext_vector_type(8))) short bf16x8;
typedef __attribute__((ext_vector_type(4))) float f32x4;
typedef __attribute__((ext_vector_type(16))) float f32x16;

#define QSCALE 0.180336880f   // 0.125 * log2(e): softmax computed in exp2 domain

#define DEV static __device__ __forceinline__

DEV u16 f2bf(float f) {
  union { float f; unsigned u; } v; v.f = f;
  unsigned r = v.u + 0x7fffu + ((v.u >> 16) & 1u);  // round-to-nearest-even
  return (u16)(r >> 16);
}

DEV unsigned pk2(float a, float b) {   // two f32 -> packed bf16x2 (RNE), low = a
  union { __hip_bfloat162 h; unsigned u; } c;
  c.h = __float22bfloat162_rn(make_float2(a, b));
  return c.u;
}

DEV void gll16(void* lds, const void* g) {
  __builtin_amdgcn_global_load_lds(
      (const __attribute__((address_space(1))) unsigned int*)g,
      (__attribute__((address_space(3))) unsigned int*)lds, 16, 0, 0);
}

// ---------------- pack: fp32 -> bf16 ----------------
__global__ __launch_bounds__(256) void cvt_f32_to_bf16(const float* __restrict__ in,
                                                       u16* __restrict__ out, int n4) {
  int i = blockIdx.x * blockDim.x + threadIdx.x;
  int stride = gridDim.x * blockDim.x;
  for (; i < n4; i += stride) {
    float4 f = ((const float4*)in)[i];
    ushort4 u;
    u.x = f2bf(f.x); u.y = f2bf(f.y); u.z = f2bf(f.z); u.w = f2bf(f.w);
    ((ushort4*)out)[i] = u;
  }
}

// ---------------- pack: W[K][N] fp32 -> Wt[N][K] bf16, cols < sn scaled ----------------
__global__ __launch_bounds__(256) void transpose_cvt(const float* __restrict__ W,
                                                     u16* __restrict__ Wt,
                                                     int K, int N, int sn, float sval) {
  __shared__ u16 t[64][65];
  const int k0 = blockIdx.x * 64, n0 = blockIdx.y * 64;
  const int tid = threadIdx.x;
  const int rr = tid >> 4;        // 0..15
  const int cc = (tid & 15) * 4;  // 0..60
  const float scl = (n0 < sn) ? sval : 1.0f;
#pragma unroll
  for (int i = 0; i < 4; ++i) {
    const int row = rr * 4 + i;
    float4 f = *(const float4*)&W[(size_t)(k0 + row) * N + n0 + cc];
    t[row][cc + 0] = f2bf(f.x * scl);
    t[row][cc + 1] = f2bf(f.y * scl);
    t[row][cc + 2] = f2bf(f.z * scl);
    t[row][cc + 3] = f2bf(f.w * scl);
  }
  __syncthreads();
#pragma unroll
  for (int i = 0; i < 4; ++i) {
    const int n = rr * 4 + i;
    ushort4 u;
    u.x = t[cc + 0][n]; u.y = t[cc + 1][n]; u.z = t[cc + 2][n]; u.w = t[cc + 3][n];
    *(ushort4*)&Wt[(size_t)(n0 + n) * K + k0 + cc] = u;
  }
}

// ---------------- transpose V part of qkv: -> vT[bh][d][t] ----------------
__global__ __launch_bounds__(256) void transpose_v(const u16* __restrict__ qkv,
                                                   u16* __restrict__ vT) {
  __shared__ u16 t[64][72];
  const int bh = blockIdx.y;          // b*16+h
  const int b = bh >> 4, h = bh & 15;
  const int t0 = blockIdx.x * 64;
  const int tid = threadIdx.x;
  const int row = tid >> 2;           // token within tile, 0..63
  const int cg = (tid & 3) * 16;      // d group
  const size_t src = (size_t)b * 2048 * 3072 + (size_t)(t0 + row) * 3072 + 2048 + h * 64 + cg;
  bf16x8 v0 = *(const bf16x8*)&qkv[src];
  bf16x8 v1 = *(const bf16x8*)&qkv[src + 8];
#pragma unroll
  for (int i = 0; i < 8; ++i) { t[row][cg + i] = (u16)v0[i]; t[row][cg + 8 + i] = (u16)v1[i]; }
  __syncthreads();
  const int d = tid >> 2;             // 0..63
  const int tg = (tid & 3) * 16;
  bf16x8 o0, o1;
#pragma unroll
  for (int i = 0; i < 8; ++i) { o0[i] = (short)t[tg + i][d]; o1[i] = (short)t[tg + 8 + i][d]; }
  u16* dst = &vT[((size_t)bh * 64 + d) * 2048 + t0 + tg];
  *(bf16x8*)dst = o0;
  *(bf16x8*)(dst + 8) = o1;
}

// ---------------- GEMM1: 256x256 tile, BK=32, 4-slot counted-vmcnt ring ------------
// (r12-verified; unchanged)

#define G1_STAGE(S)                                                   \
  {                                                                   \
    gll16((u16*)L1[S] + wave * 512, g0); g0 += 32;                    \
    gll16((u16*)L1[S] + 4096 + wave * 512, g1); g1 += 32;             \
    gll16((u16*)L1[S] + 8192 + wave * 512, g2); g2 += 32;             \
    gll16((u16*)L1[S] + 12288 + wave * 512, g3); g3 += 32;            \
  }

#define G1_BODY(S, ISSUE, VM)                                         \
  {                                                                   \
    if (ISSUE) G1_STAGE((S + 2) & 3)                                  \
    asm volatile("s_waitcnt vmcnt(" #VM ")" ::: "memory");            \
    __builtin_amdgcn_s_barrier();                                     \
    const char* sb = (const char*)L1[S];                              \
    bf16x8 af[8], bfr[4];                                             \
    _Pragma("unroll")                                                 \
    for (int m = 0; m < 8; ++m) af[m] = *(const bf16x8*)(sb + aoff[m]); \
    _Pragma("unroll")                                                 \
    for (int n = 0; n < 4; ++n) bfr[n] = *(const bf16x8*)(sb + boff[n]); \
    __builtin_amdgcn_s_setprio(1);                                    \
    _Pragma("unroll")                                                 \
    for (int m = 0; m < 8; ++m)                                       \
      _Pragma("unroll")                                               \
      for (int n = 0; n < 4; ++n)                                     \
        acc[m][n] = __builtin_amdgcn_mfma_f32_16x16x32_bf16(af[m], bfr[n], acc[m][n], 0, 0, 0); \
    __builtin_amdgcn_s_setprio(0);                                    \
  }

__global__ __launch_bounds__(512, 2) void gemm1_256(const u16* __restrict__ A,
                                                    const u16* __restrict__ Bt,
                                                    const float* __restrict__ bias,
                                                    u16* __restrict__ C) {
  __shared__ __align__(16) u16 L1[4][16384];   // 4 slots x 32KB = 128KB
  const int tid = threadIdx.x;
  const int wave = tid >> 6, lane = tid & 63;
  const int g = lane >> 4, lr = lane & 15;
  const int wr = wave >> 2, wc = wave & 3;     // 2M x 4N wave grid
  const int id = blockIdx.x;                   // 384 blocks
  const int xcd = id & 7, j = id >> 3;         // j in 0..47
  const int bm = (xcd * 4 + (j & 3)) * 256;
  const int bn = (j >> 2) * 256;

  int aoff[8], boff[4];
#pragma unroll
  for (int m = 0; m < 8; ++m)
    aoff[m] = wr * 8192 + m * 1024 + g * 256 + lr * 16;
#pragma unroll
  for (int n = 0; n < 4; ++n)
    boff[n] = 16384 + wc * 4096 + n * 1024 + g * 256 + lr * 16;

  const u16* g0; const u16* g1; const u16* g2; const u16* g3;
  {
    const int b0 = wave * 1024 + lane * 16;
    const int plane = b0 >> 8, lrr = (b0 >> 4) & 15, pb = b0 & 15;
    const int row = (plane >> 2) * 16 + lrr;
    const int kc = (plane & 3) * 8 + (pb >> 1);
    g0 = A  + (size_t)(bm + row) * 1024 + kc;
    g1 = A  + (size_t)(bm + 128 + row) * 1024 + kc;
    g2 = Bt + (size_t)(bn + row) * 1024 + kc;
    g3 = Bt + (size_t)(bn + 128 + row) * 1024 + kc;
  }

  f32x4 acc[8][4] = {};

  G1_STAGE(0)
  G1_STAGE(1)

  for (int it = 0; it < 7; ++it) {
    G1_BODY(0, 1, 8) G1_BODY(1, 1, 8) G1_BODY(2, 1, 8) G1_BODY(3, 1, 8)
  }
  G1_BODY(0, 1, 8)
  G1_BODY(1, 1, 8)
  G1_BODY(2, 0, 4)
  G1_BODY(3, 0, 0)

#pragma unroll
  for (int m = 0; m < 8; ++m) {
#pragma unroll
    for (int n = 0; n < 4; ++n) {
      const int col = bn + wc * 64 + n * 16 + lr;
      float bv = bias[col];
      if (col < 1024) bv *= QSCALE;
#pragma unroll
      for (int r = 0; r < 4; ++r) {
        const int row = bm + wr * 128 + m * 16 + g * 4 + r;
        C[(size_t)row * 3072 + col] = f2bf(acc[m][n][r] + bv);
      }
    }
  }
}

// ---------------- bf16 GEMM (gemm2): 128x128 tile, m97 structure ----------------
template<bool OUT_BF16>
__global__ __launch_bounds__(256) void gemm_bf16(const u16* __restrict__ A,
                                                 const u16* __restrict__ Bt,
                                                 const float* __restrict__ bias,
                                                 void* __restrict__ Cout,
                                                 int M, int N, int K, int qn) {
  __shared__ __align__(16) u16 As[128][64];
  __shared__ __align__(16) u16 Bs[128][64];
  const int tid = threadIdx.x;
  const int wave = tid >> 6, lane = tid & 63;
  const int g = lane >> 4, lr = lane & 15;
  const int lid = blockIdx.y * gridDim.x + blockIdx.x;
  const int chunk = gridDim.x >> 3;
  const int xcd = lid & 7, j = lid >> 3;
  const int bm = (xcd * chunk + (j % chunk)) * 128;
  const int bn = (j / chunk) * 128;
  const int wm = (wave >> 1) * 64, wn = (wave & 1) * 64;
  f32x4 acc[4][4] = {};
  for (int kt = 0; kt < K; kt += 64) {
    __syncthreads();
#pragma unroll
    for (int jj = 0; jj < 4; ++jj) {
      int chnk = wave * 4 + jj;
      int e = chnk * 512 + lane * 8;
      int r = e >> 6, c = e & 63;
      gll16((u16*)As + chnk * 512, &A[(size_t)(bm + r) * K + kt + c]);
      gll16((u16*)Bs + chnk * 512, &Bt[(size_t)(bn + r) * K + kt + c]);
    }
    __syncthreads();
#pragma unroll
    for (int kk = 0; kk < 64; kk += 32) {
      bf16x8 af[4], bfr[4];
#pragma unroll
      for (int m = 0; m < 4; ++m)
        af[m] = *(const bf16x8*)&As[wm + m * 16 + lr][kk + g * 8];
#pragma unroll
      for (int n = 0; n < 4; ++n)
        bfr[n] = *(const bf16x8*)&Bs[wn + n * 16 + lr][kk + g * 8];
#pragma unroll
      for (int m = 0; m < 4; ++m)
#pragma unroll
        for (int n = 0; n < 4; ++n)
          acc[m][n] = __builtin_amdgcn_mfma_f32_16x16x32_bf16(af[m], bfr[n], acc[m][n], 0, 0, 0);
    }
  }
#pragma unroll
  for (int m = 0; m < 4; ++m) {
#pragma unroll
    for (int n = 0; n < 4; ++n) {
      const int col = bn + wn + n * 16 + lr;
      float bv = bias ? bias[col] : 0.f;
      if (col < qn) bv *= QSCALE;
#pragma unroll
      for (int r = 0; r < 4; ++r) {
        const int row = bm + wm + m * 16 + g * 4 + r;
        float v = acc[m][n][r] + bv;
        if (OUT_BF16) ((u16*)Cout)[(size_t)row * N + col] = f2bf(v);
        else          ((float*)Cout)[(size_t)row * N + col] = v;
      }
    }
  }
}

// ---------------- flash attention: T15 2-deep pipeline (QK(t+1) || finish(t)) -------
// r12/r9 base: 256 thr / 4 waves, (256,4) -> 128-VGPR cap (r13 lesson: 8 waves/SIMD
// is VGPR-infeasible). 1024 blocks, XCD affinity. 32x32 MFMA swapped QK, in-reg P,
// static-max softmax, plane LDS (0 conflicts).
// NEW: software pipeline depth 2 within each wave. Body t:
//   {vmcnt(2); barrier; issue stage(t+3); QK(t+1)->sN [matrix pipe, background];
//    finish(t): exp2/pack/PV using sC [VALU overlaps QK execution]}
// Safety (same one-barrier-separation as r9, distance 3):
//  - stage(t+3) overwrites slot t-1; its last reads (PV(t-1)) are data-consumed
//    before barrier t, and the issue is AFTER barrier t -> no race.
//  - QK(t+1) reads slot t+1: every wave's slot-(t+1) loads retired by its vmcnt(2)
//    before barrier t (issued 2 bodies earlier -> no stall).
// Prologue stages slots 0..2, QK(0). Tail: bodies 61/62 skip issue, vmcnt 2->0.

#define ATTN_T15(SLOT, SFIN, SQK, ISS, VM, DOQK)                                  \
  {                                                                               \
    asm volatile("s_waitcnt vmcnt(" #VM ")" ::: "memory");                        \
    __builtin_amdgcn_s_barrier();                                                 \
    if (ISS) {                                                                    \
      gll16((u16*)Ks[((SLOT) + 3) & 3] + wave * 512, gk); gk += 32 * 3072;        \
      gll16((u16*)Vs[((SLOT) + 3) & 3] + wave * 512, gv); gv += 32;               \
    }                                                                             \
    if (DOQK) {                                                                   \
      const char* kb = (const char*)Ks[((SLOT) + 1) & 3];                         \
      _Pragma("unroll")                                                           \
      for (int r = 0; r < 16; ++r) SQK[r] = 0.f;                                  \
      __builtin_amdgcn_s_setprio(1);                                              \
      _Pragma("unroll")                                                           \
      for (int kk = 0; kk < 4; ++kk) {                                            \
        bf16x8 kf = *(const bf16x8*)(kb + pob + kk * 1024);                       \
        SQK = __builtin_amdgcn_mfma_f32_32x32x16_bf16(kf, qf[kk], SQK, 0, 0, 0);  \
      }                                                                           \
      __builtin_amdgcn_s_setprio(0);                                              \
    }                                                                             \
    const char* vb = (const char*)Vs[(SLOT)];                                     \
    float pr[16];                                                                 \
    _Pragma("unroll")                                                             \
    for (int r = 0; r < 16; ++r) pr[r] = __builtin_amdgcn_exp2f(SFIN[r]);         \
    lsum += ((pr[0] + pr[1]) + (pr[2] + pr[3])) + ((pr[4] + pr[5]) + (pr[6] + pr[7])) \
          + ((pr[8] + pr[9]) + (pr[10] + pr[11])) + ((pr[12] + pr[13]) + (pr[14] + pr[15])); \
    union { unsigned u[4]; bf16x8 v; } pa0, pa1;                                  \
    {                                                                             \
      unsigned X0 = pk2(pr[0], pr[1]), X1 = pk2(pr[2], pr[3]);                    \
      unsigned Y0 = pk2(pr[4], pr[5]), Y1 = pk2(pr[6], pr[7]);                    \
      asm volatile("v_permlane32_swap_b32 %0, %1" : "+v"(X0), "+v"(Y0));          \
      asm volatile("v_permlane32_swap_b32 %0, %1" : "+v"(X1), "+v"(Y1));          \
      pa0.u[0] = X0; pa0.u[1] = X1; pa0.u[2] = Y0; pa0.u[3] = Y1;                 \
      unsigned Z0 = pk2(pr[8], pr[9]), Z1 = pk2(pr[10], pr[11]);                  \
      unsigned W0 = pk2(pr[12], pr[13]), W1 = pk2(pr[14], pr[15]);                \
      asm volatile("v_permlane32_swap_b32 %0, %1" : "+v"(Z0), "+v"(W0));          \
      asm volatile("v_permlane32_swap_b32 %0, %1" : "+v"(Z1), "+v"(W1));          \
      pa1.u[0] = Z0; pa1.u[1] = Z1; pa1.u[2] = W0; pa1.u[3] = W1;                 \
    }                                                                             \
    __builtin_amdgcn_s_setprio(1);                                                \
    {                                                                             \
      bf16x8 vf00 = *(const bf16x8*)(vb + pob);                                   \
      bf16x8 vf10 = *(const bf16x8*)(vb + pob + 2048);                            \
      o0 = __builtin_amdgcn_mfma_f32_32x32x16_bf16(pa0.v, vf00, o0, 0, 0, 0);     \
      o1 = __builtin_amdgcn_mfma_f32_32x32x16_bf16(pa0.v, vf10, o1, 0, 0, 0);     \
      bf16x8 vf01 = *(const bf16x8*)(vb + pob + 1024);                            \
      bf16x8 vf11 = *(const bf16x8*)(vb + pob + 3072);                            \
      o0 = __builtin_amdgcn_mfma_f32_32x32x16_bf16(pa1.v, vf01, o0, 0, 0, 0);     \
      o1 = __builtin_amdgcn_mfma_f32_32x32x16_bf16(pa1.v, vf11, o1, 0, 0, 0);     \
    }                                                                             \
    __builtin_amdgcn_s_setprio(0);                                                \
  }

__global__ __launch_bounds__(256, 4) void attn_kernel(const u16* __restrict__ qkv,
                                                      const u16* __restrict__ vT,
                                                      u16* __restrict__ out) {
  __shared__ __align__(16) u16 Ks[4][2048];   // 4 slots x 8 planes x 512B (K)
  __shared__ __align__(16) u16 Vs[4][2048];   // 4 slots x 8 planes x 512B (V)
  const int tid = threadIdx.x;
  const int wave = tid >> 6, lane = tid & 63;
  const int hi = lane >> 5, l31 = lane & 31;
  const int id = blockIdx.x;
  const int bh = ((id >> 3) & 7) * 8 + (id & 7);   // XCD affinity: id%8 = bh%8
  const int b = bh >> 4, h = bh & 15;
  const int q0 = (id >> 6) * 128;
  const size_t base = (size_t)b * 2048 * 3072;
  const u16* kg = qkv + base + 1024 + h * 64;        // + t*3072 + d
  const u16* vg = vT + (size_t)bh * 64 * 2048;       // + d*2048 + t

  const int qrow = q0 + wave * 32 + l31;
  bf16x8 qf[4];
#pragma unroll
  for (int kk = 0; kk < 4; ++kk)
    qf[kk] = *(const bf16x8*)&qkv[base + (size_t)qrow * 3072 + h * 64 + kk * 16 + hi * 8];

  // single plane-layout base; per-fragment deltas are compile-time ds_read offsets
  const int pob = hi * 512 + l31 * 16;

  const u16* gk = kg + (size_t)l31 * 3072 + wave * 16 + hi * 8;
  const u16* gv = vg + (size_t)((wave >> 1) * 32 + l31) * 2048 + (wave & 1) * 16 + hi * 8;

  f32x16 o0 = {}, o1 = {};
  float lsum = 0.f;
  f32x16 sA, sB;

  // prologue: stage slots 0,1,2 (6 loads)
  gll16((u16*)Ks[0] + wave * 512, gk); gk += 32 * 3072;
  gll16((u16*)Vs[0] + wave * 512, gv); gv += 32;
  gll16((u16*)Ks[1] + wave * 512, gk); gk += 32 * 3072;
  gll16((u16*)Vs[1] + wave * 512, gv); gv += 32;
  gll16((u16*)Ks[2] + wave * 512, gk); gk += 32 * 3072;
  gll16((u16*)Vs[2] + wave * 512, gv); gv += 32;
  asm volatile("s_waitcnt vmcnt(4)" ::: "memory");   // slot 0 retired
  __builtin_amdgcn_s_barrier();

  // QK(0) -> sA
  {
    const char* kb = (const char*)Ks[0];
#pragma unroll
    for (int r = 0; r < 16; ++r) sA[r] = 0.f;
    __builtin_amdgcn_s_setprio(1);
#pragma unroll
    for (int kk = 0; kk < 4; ++kk) {
      bf16x8 kf = *(const bf16x8*)(kb + pob + kk * 1024);
      sA = __builtin_amdgcn_mfma_f32_32x32x16_bf16(kf, qf[kk], sA, 0, 0, 0);
    }
    __builtin_amdgcn_s_setprio(0);
  }

  // bodies 0..59 (body t: SLOT=t&3, fin s[t&1], qk s[(t+1)&1], issue stage(t+3))
  for (int it = 0; it < 15; ++it) {
    ATTN_T15(0, sA, sB, 1, 2, 1)
    ATTN_T15(1, sB, sA, 1, 2, 1)
    ATTN_T15(2, sA, sB, 1, 2, 1)
    ATTN_T15(3, sB, sA, 1, 2, 1)
  }
  ATTN_T15(0, sA, sB, 1, 2, 1)   // body 60: stages tile 63
  ATTN_T15(1, sB, sA, 0, 2, 1)   // body 61
  ATTN_T15(2, sA, sB, 0, 0, 1)   // body 62: QK(63)
  ATTN_T15(3, sB, sA, 0, 0, 0)   // body 63: finish only

  // final: row-sum across lane halves, divide, store
  float lt = lsum + __shfl_xor(lsum, 32);
  const size_t orow0 = (size_t)b * 2048 + q0 + wave * 32;
#pragma unroll
  for (int r = 0; r < 16; ++r) {
    const int crow = (r & 3) + 8 * (r >> 2) + 4 * hi;
    const float li = __shfl(lt, crow);
    u16* orow = out + (orow0 + crow) * 1024 + h * 64 + l31;
    orow[0]  = f2bf(o0[r] / li);
    orow[32] = f2bf(o1[r] / li);
  }
}

// ---------------- launcher ----------------
extern "C" void kernel_launch(void* const* d_in, const int* in_sizes, int n_in,
                              void* d_out, int out_size, void* d_ws, size_t ws_size,
                              hipStream_t stream) {
  (void)in_sizes; (void)n_in; (void)out_size; (void)ws_size;
  const float* x     = (const float*)d_in[0];  // [4,2048,1024]
  const float* w_in  = (const float*)d_in[1];  // [1024,3072]
  const float* b_in  = (const float*)d_in[2];  // [3072]
  const float* w_out = (const float*)d_in[3];  // [1024,1024]
  const float* b_out = (const float*)d_in[4];  // [1024]
  float* out = (float*)d_out;                  // [4,2048,1024] fp32

  char* ws = (char*)d_ws;
  u16* Xbf   = (u16*)ws; ws += (size_t)8192 * 1024 * 2;  // 16.8 MB (reused as vT)
  u16* WinT  = (u16*)ws; ws += (size_t)3072 * 1024 * 2;  //  6.3 MB
  u16* WoutT = (u16*)ws; ws += (size_t)1024 * 1024 * 2;  //  2.1 MB
  u16* qkv   = (u16*)ws; ws += (size_t)8192 * 3072 * 2;  // 50.3 MB
  u16* attno = (u16*)ws;                                  // 16.8 MB (total ~92.3 MB)
  u16* vT    = Xbf;   // alias: Xbf dead after gemm1; transpose_v runs after (stream-ordered)

  cvt_f32_to_bf16<<<2048, 256, 0, stream>>>(x, Xbf, 8192 * 1024 / 4);
  transpose_cvt<<<dim3(16, 48), 256, 0, stream>>>(w_in, WinT, 1024, 3072, 1024, QSCALE);
  transpose_cvt<<<dim3(16, 16), 256, 0, stream>>>(w_out, WoutT, 1024, 1024, 0, 1.0f);
  gemm1_256<<<384, 512, 0, stream>>>(Xbf, WinT, b_in, qkv);
  transpose_v<<<dim3(32, 64), 256, 0, stream>>>(qkv, vT);
  attn_kernel<<<1024, 256, 0, stream>>>(qkv, vT, attno);
  gemm_bf16<false><<<dim3(64, 8), 256, 0, stream>>>(attno, WoutT, b_out, out, 8192, 1024, 1024, 0);
}

// Round 15
// 220.986 us; speedup vs baseline: 3.1061x; 1.0153x over previous
//
#include <hip/hip_runtime.h>
#include <hip/hip_bf16.h>

typedef unsigned short u16;
typedef __attribute__((ext_vector_type(8))) short bf16x8;
typedef __attribute__((ext_vector_type(4))) float f32x4;
typedef __attribute__((ext_vector_type(16))) float f32x16;

#define QSCALE 0.180336880f   // 0.125 * log2(e): softmax computed in exp2 domain

#define DEV static __device__ __forceinline__

DEV u16 f2bf(float f) {
  union { float f; unsigned u; } v; v.f = f;
  unsigned r = v.u + 0x7fffu + ((v.u >> 16) & 1u);  // round-to-nearest-even
  return (u16)(r >> 16);
}

DEV unsigned pk2(float a, float b) {   // two f32 -> packed bf16x2 (RNE), low = a
  union { __hip_bfloat162 h; unsigned u; } c;
  c.h = __float22bfloat162_rn(make_float2(a, b));
  return c.u;
}

DEV void gll16(void* lds, const void* g) {
  __builtin_amdgcn_global_load_lds(
      (const __attribute__((address_space(1))) unsigned int*)g,
      (__attribute__((address_space(3))) unsigned int*)lds, 16, 0, 0);
}

// ---------------- fused packs: x->bf16, w_in->WinT (QSCALE'd Q cols), w_out->WoutT --
DEV void transpose_tile(const float* __restrict__ W, u16* __restrict__ Wt,
                        int K, int N, int k0, int n0, float scl, int tid,
                        u16 (*t)[65]) {
  const int rr = tid >> 4;        // 0..15
  const int cc = (tid & 15) * 4;  // 0..60
#pragma unroll
  for (int i = 0; i < 4; ++i) {
    const int row = rr * 4 + i;
    float4 f = *(const float4*)&W[(size_t)(k0 + row) * N + n0 + cc];
    t[row][cc + 0] = f2bf(f.x * scl);
    t[row][cc + 1] = f2bf(f.y * scl);
    t[row][cc + 2] = f2bf(f.z * scl);
    t[row][cc + 3] = f2bf(f.w * scl);
  }
  __syncthreads();
#pragma unroll
  for (int i = 0; i < 4; ++i) {
    const int n = rr * 4 + i;
    ushort4 u;
    u.x = t[cc + 0][n]; u.y = t[cc + 1][n]; u.z = t[cc + 2][n]; u.w = t[cc + 3][n];
    *(ushort4*)&Wt[(size_t)(n0 + n) * K + k0 + cc] = u;
  }
}

__global__ __launch_bounds__(256) void pack_all(const float* __restrict__ x,
                                                const float* __restrict__ w_in,
                                                const float* __restrict__ w_out,
                                                u16* __restrict__ Xbf,
                                                u16* __restrict__ WinT,
                                                u16* __restrict__ WoutT) {
  __shared__ u16 t[64][65];
  const int bid = blockIdx.x;
  const int tid = threadIdx.x;
  if (bid < 2048) {                       // x: [8192][1024] fp32 -> bf16
    const int n4 = 8192 * 1024 / 4;
    for (int i = bid * 256 + tid; i < n4; i += 2048 * 256) {
      float4 f = ((const float4*)x)[i];
      ushort4 u;
      u.x = f2bf(f.x); u.y = f2bf(f.y); u.z = f2bf(f.z); u.w = f2bf(f.w);
      ((ushort4*)Xbf)[i] = u;
    }
  } else if (bid < 2048 + 768) {          // w_in [1024][3072] -> WinT [3072][1024]
    const int tb = bid - 2048;            // 16 x 48 tiles
    const int k0 = (tb & 15) * 64, n0 = (tb >> 4) * 64;
    const float scl = (n0 < 1024) ? QSCALE : 1.0f;   // Q cols pre-scaled
    transpose_tile(w_in, WinT, 1024, 3072, k0, n0, scl, tid, t);
  } else {                                // w_out [1024][1024] -> WoutT [1024][1024]
    const int tb = bid - 2816;            // 16 x 16 tiles
    const int k0 = (tb & 15) * 64, n0 = (tb >> 4) * 64;
    transpose_tile(w_out, WoutT, 1024, 1024, k0, n0, 1.0f, tid, t);
  }
}

// ---------------- transpose V part of qkv: -> vT[bh][d][t] ----------------
__global__ __launch_bounds__(256) void transpose_v(const u16* __restrict__ qkv,
                                                   u16* __restrict__ vT) {
  __shared__ u16 t[64][72];
  const int bh = blockIdx.y;          // b*16+h
  const int b = bh >> 4, h = bh & 15;
  const int t0 = blockIdx.x * 64;
  const int tid = threadIdx.x;
  const int row = tid >> 2;           // token within tile, 0..63
  const int cg = (tid & 3) * 16;      // d group
  const size_t src = (size_t)b * 2048 * 3072 + (size_t)(t0 + row) * 3072 + 2048 + h * 64 + cg;
  bf16x8 v0 = *(const bf16x8*)&qkv[src];
  bf16x8 v1 = *(const bf16x8*)&qkv[src + 8];
#pragma unroll
  for (int i = 0; i < 8; ++i) { t[row][cg + i] = (u16)v0[i]; t[row][cg + 8 + i] = (u16)v1[i]; }
  __syncthreads();
  const int d = tid >> 2;             // 0..63
  const int tg = (tid & 3) * 16;
  bf16x8 o0, o1;
#pragma unroll
  for (int i = 0; i < 8; ++i) { o0[i] = (short)t[tg + i][d]; o1[i] = (short)t[tg + 8 + i][d]; }
  u16* dst = &vT[((size_t)bh * 64 + d) * 2048 + t0 + tg];
  *(bf16x8*)dst = o0;
  *(bf16x8*)(dst + 8) = o1;
}

// ---------------- GEMM1: 256x256 tile, BK=32, 4-slot counted-vmcnt ring ------------
// (r12-verified; unchanged)

#define G1_STAGE(S)                                                   \
  {                                                                   \
    gll16((u16*)L1[S] + wave * 512, g0); g0 += 32;                    \
    gll16((u16*)L1[S] + 4096 + wave * 512, g1); g1 += 32;             \
    gll16((u16*)L1[S] + 8192 + wave * 512, g2); g2 += 32;             \
    gll16((u16*)L1[S] + 12288 + wave * 512, g3); g3 += 32;            \
  }

#define G1_BODY(S, ISSUE, VM)                                         \
  {                                                                   \
    if (ISSUE) G1_STAGE((S + 2) & 3)                                  \
    asm volatile("s_waitcnt vmcnt(" #VM ")" ::: "memory");            \
    __builtin_amdgcn_s_barrier();                                     \
    const char* sb = (const char*)L1[S];                              \
    bf16x8 af[8], bfr[4];                                             \
    _Pragma("unroll")                                                 \
    for (int m = 0; m < 8; ++m) af[m] = *(const bf16x8*)(sb + aoff[m]); \
    _Pragma("unroll")                                                 \
    for (int n = 0; n < 4; ++n) bfr[n] = *(const bf16x8*)(sb + boff[n]); \
    __builtin_amdgcn_s_setprio(1);                                    \
    _Pragma("unroll")                                                 \
    for (int m = 0; m < 8; ++m)                                       \
      _Pragma("unroll")                                               \
      for (int n = 0; n < 4; ++n)                                     \
        acc[m][n] = __builtin_amdgcn_mfma_f32_16x16x32_bf16(af[m], bfr[n], acc[m][n], 0, 0, 0); \
    __builtin_amdgcn_s_setprio(0);                                    \
  }

__global__ __launch_bounds__(512, 2) void gemm1_256(const u16* __restrict__ A,
                                                    const u16* __restrict__ Bt,
                                                    const float* __restrict__ bias,
                                                    u16* __restrict__ C) {
  __shared__ __align__(16) u16 L1[4][16384];   // 4 slots x 32KB = 128KB
  const int tid = threadIdx.x;
  const int wave = tid >> 6, lane = tid & 63;
  const int g = lane >> 4, lr = lane & 15;
  const int wr = wave >> 2, wc = wave & 3;     // 2M x 4N wave grid
  const int id = blockIdx.x;                   // 384 blocks
  const int xcd = id & 7, j = id >> 3;         // j in 0..47
  const int bm = (xcd * 4 + (j & 3)) * 256;
  const int bn = (j >> 2) * 256;

  int aoff[8], boff[4];
#pragma unroll
  for (int m = 0; m < 8; ++m)
    aoff[m] = wr * 8192 + m * 1024 + g * 256 + lr * 16;
#pragma unroll
  for (int n = 0; n < 4; ++n)
    boff[n] = 16384 + wc * 4096 + n * 1024 + g * 256 + lr * 16;

  const u16* g0; const u16* g1; const u16* g2; const u16* g3;
  {
    const int b0 = wave * 1024 + lane * 16;
    const int plane = b0 >> 8, lrr = (b0 >> 4) & 15, pb = b0 & 15;
    const int row = (plane >> 2) * 16 + lrr;
    const int kc = (plane & 3) * 8 + (pb >> 1);
    g0 = A  + (size_t)(bm + row) * 1024 + kc;
    g1 = A  + (size_t)(bm + 128 + row) * 1024 + kc;
    g2 = Bt + (size_t)(bn + row) * 1024 + kc;
    g3 = Bt + (size_t)(bn + 128 + row) * 1024 + kc;
  }

  f32x4 acc[8][4] = {};

  G1_STAGE(0)
  G1_STAGE(1)

  for (int it = 0; it < 7; ++it) {
    G1_BODY(0, 1, 8) G1_BODY(1, 1, 8) G1_BODY(2, 1, 8) G1_BODY(3, 1, 8)
  }
  G1_BODY(0, 1, 8)
  G1_BODY(1, 1, 8)
  G1_BODY(2, 0, 4)
  G1_BODY(3, 0, 0)

#pragma unroll
  for (int m = 0; m < 8; ++m) {
#pragma unroll
    for (int n = 0; n < 4; ++n) {
      const int col = bn + wc * 64 + n * 16 + lr;
      float bv = bias[col];
      if (col < 1024) bv *= QSCALE;
#pragma unroll
      for (int r = 0; r < 4; ++r) {
        const int row = bm + wr * 128 + m * 16 + g * 4 + r;
        C[(size_t)row * 3072 + col] = f2bf(acc[m][n][r] + bv);
      }
    }
  }
}

// ---------------- bf16 GEMM (gemm2): 128x128 tile, m97 structure ----------------
template<bool OUT_BF16>
__global__ __launch_bounds__(256) void gemm_bf16(const u16* __restrict__ A,
                                                 const u16* __restrict__ Bt,
                                                 const float* __restrict__ bias,
                                                 void* __restrict__ Cout,
                                                 int M, int N, int K, int qn) {
  __shared__ __align__(16) u16 As[128][64];
  __shared__ __align__(16) u16 Bs[128][64];
  const int tid = threadIdx.x;
  const int wave = tid >> 6, lane = tid & 63;
  const int g = lane >> 4, lr = lane & 15;
  const int lid = blockIdx.y * gridDim.x + blockIdx.x;
  const int chunk = gridDim.x >> 3;
  const int xcd = lid & 7, j = lid >> 3;
  const int bm = (xcd * chunk + (j % chunk)) * 128;
  const int bn = (j / chunk) * 128;
  const int wm = (wave >> 1) * 64, wn = (wave & 1) * 64;
  f32x4 acc[4][4] = {};
  for (int kt = 0; kt < K; kt += 64) {
    __syncthreads();
#pragma unroll
    for (int jj = 0; jj < 4; ++jj) {
      int chnk = wave * 4 + jj;
      int e = chnk * 512 + lane * 8;
      int r = e >> 6, c = e & 63;
      gll16((u16*)As + chnk * 512, &A[(size_t)(bm + r) * K + kt + c]);
      gll16((u16*)Bs + chnk * 512, &Bt[(size_t)(bn + r) * K + kt + c]);
    }
    __syncthreads();
#pragma unroll
    for (int kk = 0; kk < 64; kk += 32) {
      bf16x8 af[4], bfr[4];
#pragma unroll
      for (int m = 0; m < 4; ++m)
        af[m] = *(const bf16x8*)&As[wm + m * 16 + lr][kk + g * 8];
#pragma unroll
      for (int n = 0; n < 4; ++n)
        bfr[n] = *(const bf16x8*)&Bs[wn + n * 16 + lr][kk + g * 8];
#pragma unroll
      for (int m = 0; m < 4; ++m)
#pragma unroll
        for (int n = 0; n < 4; ++n)
          acc[m][n] = __builtin_amdgcn_mfma_f32_16x16x32_bf16(af[m], bfr[n], acc[m][n], 0, 0, 0);
    }
  }
#pragma unroll
  for (int m = 0; m < 4; ++m) {
#pragma unroll
    for (int n = 0; n < 4; ++n) {
      const int col = bn + wn + n * 16 + lr;
      float bv = bias ? bias[col] : 0.f;
      if (col < qn) bv *= QSCALE;
#pragma unroll
      for (int r = 0; r < 4; ++r) {
        const int row = bm + wm + m * 16 + g * 4 + r;
        float v = acc[m][n][r] + bv;
        if (OUT_BF16) ((u16*)Cout)[(size_t)row * N + col] = f2bf(v);
        else          ((float*)Cout)[(size_t)row * N + col] = v;
      }
    }
  }
}

// ---------------- flash attention: r9/r12 kernel verbatim (verified ~101us) ---------
// 32x32 MFMA, in-reg P via cvt_pk+permlane32_swap, static-max softmax, plane LDS
// (0 conflicts), 4-buffer counted-vmcnt(4) pipeline, XCD-affine grid.

#define ATTN_BODY(BUF, ISSUE, VM)                                                 \
  {                                                                               \
    if (ISSUE) {                                                                  \
      gll16((u16*)Ks[((BUF) + 2) & 3] + wave * 512, gk); gk += 32 * 3072;         \
      gll16((u16*)Vs[((BUF) + 2) & 3] + wave * 512, gv); gv += 32;                \
    }                                                                             \
    asm volatile("s_waitcnt vmcnt(" #VM ")" ::: "memory");                        \
    __builtin_amdgcn_s_barrier();                                                 \
    const char* kb = (const char*)Ks[(BUF)];                                      \
    const char* vb = (const char*)Vs[(BUF)];                                      \
    f32x16 s = {};                                                                \
    __builtin_amdgcn_s_setprio(1);                                                \
    _Pragma("unroll")                                                             \
    for (int kk = 0; kk < 4; ++kk) {                                              \
      bf16x8 kf = *(const bf16x8*)(kb + koff[kk]);                                \
      s = __builtin_amdgcn_mfma_f32_32x32x16_bf16(kf, qf[kk], s, 0, 0, 0);        \
    }                                                                             \
    __builtin_amdgcn_s_setprio(0);                                                \
    float pr[16];                                                                 \
    _Pragma("unroll")                                                             \
    for (int r = 0; r < 16; ++r) pr[r] = __builtin_amdgcn_exp2f(s[r]);            \
    lsum += ((pr[0] + pr[1]) + (pr[2] + pr[3])) + ((pr[4] + pr[5]) + (pr[6] + pr[7])) \
          + ((pr[8] + pr[9]) + (pr[10] + pr[11])) + ((pr[12] + pr[13]) + (pr[14] + pr[15])); \
    union { unsigned u[4]; bf16x8 v; } pa0, pa1;                                  \
    {                                                                             \
      unsigned X0 = pk2(pr[0], pr[1]), X1 = pk2(pr[2], pr[3]);                    \
      unsigned Y0 = pk2(pr[4], pr[5]), Y1 = pk2(pr[6], pr[7]);                    \
      asm volatile("v_permlane32_swap_b32 %0, %1" : "+v"(X0), "+v"(Y0));          \
      asm volatile("v_permlane32_swap_b32 %0, %1" : "+v"(X1), "+v"(Y1));          \
      pa0.u[0] = X0; pa0.u[1] = X1; pa0.u[2] = Y0; pa0.u[3] = Y1;                 \
      unsigned Z0 = pk2(pr[8], pr[9]), Z1 = pk2(pr[10], pr[11]);                  \
      unsigned W0 = pk2(pr[12], pr[13]), W1 = pk2(pr[14], pr[15]);                \
      asm volatile("v_permlane32_swap_b32 %0, %1" : "+v"(Z0), "+v"(W0));          \
      asm volatile("v_permlane32_swap_b32 %0, %1" : "+v"(Z1), "+v"(W1));          \
      pa1.u[0] = Z0; pa1.u[1] = Z1; pa1.u[2] = W0; pa1.u[3] = W1;                 \
    }                                                                             \
    __builtin_amdgcn_s_setprio(1);                                                \
    {                                                                             \
      bf16x8 vf00 = *(const bf16x8*)(vb + voff[0][0]);                            \
      bf16x8 vf10 = *(const bf16x8*)(vb + voff[1][0]);                            \
      o0 = __builtin_amdgcn_mfma_f32_32x32x16_bf16(pa0.v, vf00, o0, 0, 0, 0);     \
      o1 = __builtin_amdgcn_mfma_f32_32x32x16_bf16(pa0.v, vf10, o1, 0, 0, 0);     \
      bf16x8 vf01 = *(const bf16x8*)(vb + voff[0][1]);                            \
      bf16x8 vf11 = *(const bf16x8*)(vb + voff[1][1]);                            \
      o0 = __builtin_amdgcn_mfma_f32_32x32x16_bf16(pa1.v, vf01, o0, 0, 0, 0);     \
      o1 = __builtin_amdgcn_mfma_f32_32x32x16_bf16(pa1.v, vf11, o1, 0, 0, 0);     \
    }                                                                             \
    __builtin_amdgcn_s_setprio(0);                                                \
  }

__global__ __launch_bounds__(256, 4) void attn_kernel(const u16* __restrict__ qkv,
                                                      const u16* __restrict__ vT,
                                                      u16* __restrict__ out) {
  __shared__ __align__(16) u16 Ks[4][2048];   // 4 bufs x 8 planes x 512B (K)
  __shared__ __align__(16) u16 Vs[4][2048];   // 4 bufs x 8 planes x 512B (V)
  const int tid = threadIdx.x;
  const int wave = tid >> 6, lane = tid & 63;
  const int hi = lane >> 5, l31 = lane & 31;
  const int id = blockIdx.x;
  const int bh = ((id >> 3) & 7) * 8 + (id & 7);   // XCD affinity: id%8 = bh%8
  const int b = bh >> 4, h = bh & 15;
  const int q0 = (id >> 6) * 128;
  const size_t base = (size_t)b * 2048 * 3072;
  const u16* kg = qkv + base + 1024 + h * 64;        // + t*3072 + d
  const u16* vg = vT + (size_t)bh * 64 * 2048;       // + d*2048 + t

  const int qrow = q0 + wave * 32 + l31;
  bf16x8 qf[4];
#pragma unroll
  for (int kk = 0; kk < 4; ++kk)
    qf[kk] = *(const bf16x8*)&qkv[base + (size_t)qrow * 3072 + h * 64 + kk * 16 + hi * 8];

  int koff[4];
#pragma unroll
  for (int kk = 0; kk < 4; ++kk)
    koff[kk] = (kk * 2 + hi) * 512 + l31 * 16;
  int voff[2][2];
#pragma unroll
  for (int dt = 0; dt < 2; ++dt)
#pragma unroll
    for (int kp = 0; kp < 2; ++kp)
      voff[dt][kp] = (dt * 4 + kp * 2 + hi) * 512 + l31 * 16;

  const u16* gk = kg + (size_t)l31 * 3072 + wave * 16 + hi * 8;
  const u16* gv = vg + (size_t)((wave >> 1) * 32 + l31) * 2048 + (wave & 1) * 16 + hi * 8;

  f32x16 o0 = {}, o1 = {};
  float lsum = 0.f;

  gll16((u16*)Ks[0] + wave * 512, gk); gk += 32 * 3072;
  gll16((u16*)Vs[0] + wave * 512, gv); gv += 32;
  gll16((u16*)Ks[1] + wave * 512, gk); gk += 32 * 3072;
  gll16((u16*)Vs[1] + wave * 512, gv); gv += 32;

  for (int it4 = 0; it4 < 15; ++it4) {
    ATTN_BODY(0, true, 4)
    ATTN_BODY(1, true, 4)
    ATTN_BODY(2, true, 4)
    ATTN_BODY(3, true, 4)
  }
  ATTN_BODY(0, true, 4)    // body 60: stages tile 62
  ATTN_BODY(1, true, 4)    // body 61: stages tile 63
  ATTN_BODY(2, false, 2)   // body 62
  ATTN_BODY(3, false, 0)   // body 63

  float lt = lsum + __shfl_xor(lsum, 32);
  const size_t orow0 = (size_t)b * 2048 + q0 + wave * 32;
#pragma unroll
  for (int r = 0; r < 16; ++r) {
    const int crow = (r & 3) + 8 * (r >> 2) + 4 * hi;
    const float li = __shfl(lt, crow);
    u16* orow = out + (orow0 + crow) * 1024 + h * 64 + l31;
    orow[0]  = f2bf(o0[r] / li);
    orow[32] = f2bf(o1[r] / li);
  }
}

// ---------------- launcher ----------------
extern "C" void kernel_launch(void* const* d_in, const int* in_sizes, int n_in,
                              void* d_out, int out_size, void* d_ws, size_t ws_size,
                              hipStream_t stream) {
  (void)in_sizes; (void)n_in; (void)out_size; (void)ws_size;
  const float* x     = (const float*)d_in[0];  // [4,2048,1024]
  const float* w_in  = (const float*)d_in[1];  // [1024,3072]
  const float* b_in  = (const float*)d_in[2];  // [3072]
  const float* w_out = (const float*)d_in[3];  // [1024,1024]
  const float* b_out = (const float*)d_in[4];  // [1024]
  float* out = (float*)d_out;                  // [4,2048,1024] fp32

  char* ws = (char*)d_ws;
  u16* Xbf   = (u16*)ws; ws += (size_t)8192 * 1024 * 2;  // 16.8 MB (reused as vT)
  u16* WinT  = (u16*)ws; ws += (size_t)3072 * 1024 * 2;  //  6.3 MB
  u16* WoutT = (u16*)ws; ws += (size_t)1024 * 1024 * 2;  //  2.1 MB
  u16* qkv   = (u16*)ws; ws += (size_t)8192 * 3072 * 2;  // 50.3 MB
  u16* attno = (u16*)ws;                                  // 16.8 MB (total ~92.3 MB)
  u16* vT    = Xbf;   // alias: Xbf dead after gemm1; transpose_v runs after (stream-ordered)

  pack_all<<<3072, 256, 0, stream>>>(x, w_in, w_out, Xbf, WinT, WoutT);
  gemm1_256<<<384, 512, 0, stream>>>(Xbf, WinT, b_in, qkv);
  transpose_v<<<dim3(32, 64), 256, 0, stream>>>(qkv, vT);
  attn_kernel<<<1024, 256, 0, stream>>>(qkv, vT, attno);
  gemm_bf16<false><<<dim3(64, 8), 256, 0, stream>>>(attno, WoutT, b_out, out, 8192, 1024, 1024, 0);
}

// Round 16
// 218.030 us; speedup vs baseline: 3.1482x; 1.0136x over previous
//
#include <hip/hip_runtime.h>
#include <hip/hip_bf16.h>

typedef unsigned short u16;
typedef __attribute__((ext_vector_type(8))) short bf16x8;
typedef __attribute__((ext_vector_type(4))) float f32x4;
typedef __attribute__((ext_vector_type(16))) float f32x16;

#define QSCALE 0.180336880f   // 0.125 * log2(e): softmax computed in exp2 domain

#define DEV static __device__ __forceinline__

DEV u16 f2bf(float f) {
  union { float f; unsigned u; } v; v.f = f;
  unsigned r = v.u + 0x7fffu + ((v.u >> 16) & 1u);  // round-to-nearest-even
  return (u16)(r >> 16);
}

DEV unsigned pk2(float a, float b) {   // two f32 -> packed bf16x2 (RNE), low = a
  union { __hip_bfloat162 h; unsigned u; } c;
  c.h = __float22bfloat162_rn(make_float2(a, b));
  return c.u;
}

DEV void gll16(void* lds, const void* g) {
  __builtin_amdgcn_global_load_lds(
      (const __attribute__((address_space(1))) unsigned int*)g,
      (__attribute__((address_space(3))) unsigned int*)lds, 16, 0, 0);
}

// ---------------- fused packs: x->bf16, w_in->WinT (QSCALE'd Q cols), w_out->WoutT --
DEV void transpose_tile(const float* __restrict__ W, u16* __restrict__ Wt,
                        int K, int N, int k0, int n0, float scl, int tid,
                        u16 (*t)[65]) {
  const int rr = tid >> 4;        // 0..15
  const int cc = (tid & 15) * 4;  // 0..60
#pragma unroll
  for (int i = 0; i < 4; ++i) {
    const int row = rr * 4 + i;
    float4 f = *(const float4*)&W[(size_t)(k0 + row) * N + n0 + cc];
    t[row][cc + 0] = f2bf(f.x * scl);
    t[row][cc + 1] = f2bf(f.y * scl);
    t[row][cc + 2] = f2bf(f.z * scl);
    t[row][cc + 3] = f2bf(f.w * scl);
  }
  __syncthreads();
#pragma unroll
  for (int i = 0; i < 4; ++i) {
    const int n = rr * 4 + i;
    ushort4 u;
    u.x = t[cc + 0][n]; u.y = t[cc + 1][n]; u.z = t[cc + 2][n]; u.w = t[cc + 3][n];
    *(ushort4*)&Wt[(size_t)(n0 + n) * K + k0 + cc] = u;
  }
}

__global__ __launch_bounds__(256) void pack_all(const float* __restrict__ x,
                                                const float* __restrict__ w_in,
                                                const float* __restrict__ w_out,
                                                u16* __restrict__ Xbf,
                                                u16* __restrict__ WinT,
                                                u16* __restrict__ WoutT) {
  __shared__ u16 t[64][65];
  const int bid = blockIdx.x;
  const int tid = threadIdx.x;
  if (bid < 2048) {                       // x: [8192][1024] fp32 -> bf16
    const int n4 = 8192 * 1024 / 4;
    for (int i = bid * 256 + tid; i < n4; i += 2048 * 256) {
      float4 f = ((const float4*)x)[i];
      ushort4 u;
      u.x = f2bf(f.x); u.y = f2bf(f.y); u.z = f2bf(f.z); u.w = f2bf(f.w);
      ((ushort4*)Xbf)[i] = u;
    }
  } else if (bid < 2048 + 768) {          // w_in [1024][3072] -> WinT [3072][1024]
    const int tb = bid - 2048;            // 16 x 48 tiles
    const int k0 = (tb & 15) * 64, n0 = (tb >> 4) * 64;
    const float scl = (n0 < 1024) ? QSCALE : 1.0f;   // Q cols pre-scaled
    transpose_tile(w_in, WinT, 1024, 3072, k0, n0, scl, tid, t);
  } else {                                // w_out [1024][1024] -> WoutT [1024][1024]
    const int tb = bid - 2816;            // 16 x 16 tiles
    const int k0 = (tb & 15) * 64, n0 = (tb >> 4) * 64;
    transpose_tile(w_out, WoutT, 1024, 1024, k0, n0, 1.0f, tid, t);
  }
}

// ---------------- transpose V part of qkv: -> vT[bh][d][t] ----------------
__global__ __launch_bounds__(256) void transpose_v(const u16* __restrict__ qkv,
                                                   u16* __restrict__ vT) {
  __shared__ u16 t[64][72];
  const int bh = blockIdx.y;          // b*16+h
  const int b = bh >> 4, h = bh & 15;
  const int t0 = blockIdx.x * 64;
  const int tid = threadIdx.x;
  const int row = tid >> 2;           // token within tile, 0..63
  const int cg = (tid & 3) * 16;      // d group
  const size_t src = (size_t)b * 2048 * 3072 + (size_t)(t0 + row) * 3072 + 2048 + h * 64 + cg;
  bf16x8 v0 = *(const bf16x8*)&qkv[src];
  bf16x8 v1 = *(const bf16x8*)&qkv[src + 8];
#pragma unroll
  for (int i = 0; i < 8; ++i) { t[row][cg + i] = (u16)v0[i]; t[row][cg + 8 + i] = (u16)v1[i]; }
  __syncthreads();
  const int d = tid >> 2;             // 0..63
  const int tg = (tid & 3) * 16;
  bf16x8 o0, o1;
#pragma unroll
  for (int i = 0; i < 8; ++i) { o0[i] = (short)t[tg + i][d]; o1[i] = (short)t[tg + 8 + i][d]; }
  u16* dst = &vT[((size_t)bh * 64 + d) * 2048 + t0 + tg];
  *(bf16x8*)dst = o0;
  *(bf16x8*)(dst + 8) = o1;
}

// ---------------- GEMM1: 256x256 tile, BK=32, 4-slot counted-vmcnt ring ------------
// (r12-verified; unchanged)

#define G1_STAGE(S)                                                   \
  {                                                                   \
    gll16((u16*)L1[S] + wave * 512, g0); g0 += 32;                    \
    gll16((u16*)L1[S] + 4096 + wave * 512, g1); g1 += 32;             \
    gll16((u16*)L1[S] + 8192 + wave * 512, g2); g2 += 32;             \
    gll16((u16*)L1[S] + 12288 + wave * 512, g3); g3 += 32;            \
  }

#define G1_BODY(S, ISSUE, VM)                                         \
  {                                                                   \
    if (ISSUE) G1_STAGE((S + 2) & 3)                                  \
    asm volatile("s_waitcnt vmcnt(" #VM ")" ::: "memory");            \
    __builtin_amdgcn_s_barrier();                                     \
    const char* sb = (const char*)L1[S];                              \
    bf16x8 af[8], bfr[4];                                             \
    _Pragma("unroll")                                                 \
    for (int m = 0; m < 8; ++m) af[m] = *(const bf16x8*)(sb + aoff[m]); \
    _Pragma("unroll")                                                 \
    for (int n = 0; n < 4; ++n) bfr[n] = *(const bf16x8*)(sb + boff[n]); \
    __builtin_amdgcn_s_setprio(1);                                    \
    _Pragma("unroll")                                                 \
    for (int m = 0; m < 8; ++m)                                       \
      _Pragma("unroll")                                               \
      for (int n = 0; n < 4; ++n)                                     \
        acc[m][n] = __builtin_amdgcn_mfma_f32_16x16x32_bf16(af[m], bfr[n], acc[m][n], 0, 0, 0); \
    __builtin_amdgcn_s_setprio(0);                                    \
  }

__global__ __launch_bounds__(512, 2) void gemm1_256(const u16* __restrict__ A,
                                                    const u16* __restrict__ Bt,
                                                    const float* __restrict__ bias,
                                                    u16* __restrict__ C) {
  __shared__ __align__(16) u16 L1[4][16384];   // 4 slots x 32KB = 128KB
  const int tid = threadIdx.x;
  const int wave = tid >> 6, lane = tid & 63;
  const int g = lane >> 4, lr = lane & 15;
  const int wr = wave >> 2, wc = wave & 3;     // 2M x 4N wave grid
  const int id = blockIdx.x;                   // 384 blocks
  const int xcd = id & 7, j = id >> 3;         // j in 0..47
  const int bm = (xcd * 4 + (j & 3)) * 256;
  const int bn = (j >> 2) * 256;

  int aoff[8], boff[4];
#pragma unroll
  for (int m = 0; m < 8; ++m)
    aoff[m] = wr * 8192 + m * 1024 + g * 256 + lr * 16;
#pragma unroll
  for (int n = 0; n < 4; ++n)
    boff[n] = 16384 + wc * 4096 + n * 1024 + g * 256 + lr * 16;

  const u16* g0; const u16* g1; const u16* g2; const u16* g3;
  {
    const int b0 = wave * 1024 + lane * 16;
    const int plane = b0 >> 8, lrr = (b0 >> 4) & 15, pb = b0 & 15;
    const int row = (plane >> 2) * 16 + lrr;
    const int kc = (plane & 3) * 8 + (pb >> 1);
    g0 = A  + (size_t)(bm + row) * 1024 + kc;
    g1 = A  + (size_t)(bm + 128 + row) * 1024 + kc;
    g2 = Bt + (size_t)(bn + row) * 1024 + kc;
    g3 = Bt + (size_t)(bn + 128 + row) * 1024 + kc;
  }

  f32x4 acc[8][4] = {};

  G1_STAGE(0)
  G1_STAGE(1)

  for (int it = 0; it < 7; ++it) {
    G1_BODY(0, 1, 8) G1_BODY(1, 1, 8) G1_BODY(2, 1, 8) G1_BODY(3, 1, 8)
  }
  G1_BODY(0, 1, 8)
  G1_BODY(1, 1, 8)
  G1_BODY(2, 0, 4)
  G1_BODY(3, 0, 0)

#pragma unroll
  for (int m = 0; m < 8; ++m) {
#pragma unroll
    for (int n = 0; n < 4; ++n) {
      const int col = bn + wc * 64 + n * 16 + lr;
      float bv = bias[col];
      if (col < 1024) bv *= QSCALE;
#pragma unroll
      for (int r = 0; r < 4; ++r) {
        const int row = bm + wr * 128 + m * 16 + g * 4 + r;
        C[(size_t)row * 3072 + col] = f2bf(acc[m][n][r] + bv);
      }
    }
  }
}

// ---------------- GEMM2: 256x128 tile, BK=32, 4-slot counted-vmcnt ring ------------
// out = attno[8192][1024] x WoutT[1024][1024]^T + b_out, fp32 out.
// Same verified structure as gemm1_256; B region is 8KB (one staging call).
// 512 thr = 8 waves (2M x 4N), wave tile 128x32, acc 8x2 = 64 VGPR.
// LDS: 4 slots x 24KB = 96KB -> 1 block/CU; grid 256 = exactly 1/CU (no tail).
// vmcnt(6) steady (3 loads/slot, 2 slots in flight); tail 3 -> 0.

#define G2_STAGE(S)                                                   \
  {                                                                   \
    gll16((u16*)L2[S] + wave * 512, g0); g0 += 32;                    \
    gll16((u16*)L2[S] + 4096 + wave * 512, g1); g1 += 32;             \
    gll16((u16*)L2[S] + 8192 + wave * 512, g2); g2 += 32;             \
  }

#define G2_BODY(S, ISSUE, VM)                                         \
  {                                                                   \
    if (ISSUE) G2_STAGE((S + 2) & 3)                                  \
    asm volatile("s_waitcnt vmcnt(" #VM ")" ::: "memory");            \
    __builtin_amdgcn_s_barrier();                                     \
    const char* sb = (const char*)L2[S];                              \
    bf16x8 af[8], bfr[2];                                             \
    _Pragma("unroll")                                                 \
    for (int m = 0; m < 8; ++m) af[m] = *(const bf16x8*)(sb + aoff[m]); \
    _Pragma("unroll")                                                 \
    for (int n = 0; n < 2; ++n) bfr[n] = *(const bf16x8*)(sb + boff[n]); \
    __builtin_amdgcn_s_setprio(1);                                    \
    _Pragma("unroll")                                                 \
    for (int m = 0; m < 8; ++m)                                       \
      _Pragma("unroll")                                               \
      for (int n = 0; n < 2; ++n)                                     \
        acc[m][n] = __builtin_amdgcn_mfma_f32_16x16x32_bf16(af[m], bfr[n], acc[m][n], 0, 0, 0); \
    __builtin_amdgcn_s_setprio(0);                                    \
  }

__global__ __launch_bounds__(512, 2) void gemm2_256(const u16* __restrict__ A,
                                                    const u16* __restrict__ Bt,
                                                    const float* __restrict__ bias,
                                                    float* __restrict__ C) {
  __shared__ __align__(16) u16 L2[4][12288];   // 4 slots x 24KB = 96KB
  const int tid = threadIdx.x;
  const int wave = tid >> 6, lane = tid & 63;
  const int g = lane >> 4, lr = lane & 15;
  const int wr = wave >> 2, wc = wave & 3;     // 2M x 4N wave grid
  const int id = blockIdx.x;                   // 256 blocks
  const int xcd = id & 7, j = id >> 3;         // j in 0..31
  const int bm = (xcd * 4 + (j & 3)) * 256;    // 32 M-tiles
  const int bn = (j >> 2) * 128;               // 8 N-tiles

  int aoff[8], boff[2];
#pragma unroll
  for (int m = 0; m < 8; ++m)
    aoff[m] = wr * 8192 + m * 1024 + g * 256 + lr * 16;
#pragma unroll
  for (int n = 0; n < 2; ++n)
    boff[n] = 16384 + (wc * 2 + n) * 1024 + g * 256 + lr * 16;

  const u16* g0; const u16* g1; const u16* g2;
  {
    const int b0 = wave * 1024 + lane * 16;    // byte offset within an 8KB half-region
    const int plane = b0 >> 8, lrr = (b0 >> 4) & 15, pb = b0 & 15;
    const int row = (plane >> 2) * 16 + lrr;   // 0..127
    const int kc = (plane & 3) * 8 + (pb >> 1);
    g0 = A  + (size_t)(bm + row) * 1024 + kc;          // A rows 0..127
    g1 = A  + (size_t)(bm + 128 + row) * 1024 + kc;    // A rows 128..255
    g2 = Bt + (size_t)(bn + row) * 1024 + kc;          // B rows 0..127
  }

  f32x4 acc[8][2] = {};

  G2_STAGE(0)
  G2_STAGE(1)

  for (int it = 0; it < 7; ++it) {             // bodies 0..27
    G2_BODY(0, 1, 6) G2_BODY(1, 1, 6) G2_BODY(2, 1, 6) G2_BODY(3, 1, 6)
  }
  G2_BODY(0, 1, 6)   // body 28 (stages 30)
  G2_BODY(1, 1, 6)   // body 29 (stages 31)
  G2_BODY(2, 0, 3)   // body 30
  G2_BODY(3, 0, 0)   // body 31

#pragma unroll
  for (int m = 0; m < 8; ++m) {
#pragma unroll
    for (int n = 0; n < 2; ++n) {
      const int col = bn + wc * 32 + n * 16 + lr;
      const float bv = bias[col];
#pragma unroll
      for (int r = 0; r < 4; ++r) {
        const int row = bm + wr * 128 + m * 16 + g * 4 + r;
        C[(size_t)row * 1024 + col] = acc[m][n][r] + bv;
      }
    }
  }
}

// ---------------- flash attention: r9/r12 kernel verbatim (verified ~101us) ---------
// 32x32 MFMA, in-reg P via cvt_pk+permlane32_swap, static-max softmax, plane LDS
// (0 conflicts), 4-buffer counted-vmcnt(4) pipeline, XCD-affine grid.

#define ATTN_BODY(BUF, ISSUE, VM)                                                 \
  {                                                                               \
    if (ISSUE) {                                                                  \
      gll16((u16*)Ks[((BUF) + 2) & 3] + wave * 512, gk); gk += 32 * 3072;         \
      gll16((u16*)Vs[((BUF) + 2) & 3] + wave * 512, gv); gv += 32;                \
    }                                                                             \
    asm volatile("s_waitcnt vmcnt(" #VM ")" ::: "memory");                        \
    __builtin_amdgcn_s_barrier();                                                 \
    const char* kb = (const char*)Ks[(BUF)];                                      \
    const char* vb = (const char*)Vs[(BUF)];                                      \
    f32x16 s = {};                                                                \
    __builtin_amdgcn_s_setprio(1);                                                \
    _Pragma("unroll")                                                             \
    for (int kk = 0; kk < 4; ++kk) {                                              \
      bf16x8 kf = *(const bf16x8*)(kb + koff[kk]);                                \
      s = __builtin_amdgcn_mfma_f32_32x32x16_bf16(kf, qf[kk], s, 0, 0, 0);        \
    }                                                                             \
    __builtin_amdgcn_s_setprio(0);                                                \
    float pr[16];                                                                 \
    _Pragma("unroll")                                                             \
    for (int r = 0; r < 16; ++r) pr[r] = __builtin_amdgcn_exp2f(s[r]);            \
    lsum += ((pr[0] + pr[1]) + (pr[2] + pr[3])) + ((pr[4] + pr[5]) + (pr[6] + pr[7])) \
          + ((pr[8] + pr[9]) + (pr[10] + pr[11])) + ((pr[12] + pr[13]) + (pr[14] + pr[15])); \
    union { unsigned u[4]; bf16x8 v; } pa0, pa1;                                  \
    {                                                                             \
      unsigned X0 = pk2(pr[0], pr[1]), X1 = pk2(pr[2], pr[3]);                    \
      unsigned Y0 = pk2(pr[4], pr[5]), Y1 = pk2(pr[6], pr[7]);                    \
      asm volatile("v_permlane32_swap_b32 %0, %1" : "+v"(X0), "+v"(Y0));          \
      asm volatile("v_permlane32_swap_b32 %0, %1" : "+v"(X1), "+v"(Y1));          \
      pa0.u[0] = X0; pa0.u[1] = X1; pa0.u[2] = Y0; pa0.u[3] = Y1;                 \
      unsigned Z0 = pk2(pr[8], pr[9]), Z1 = pk2(pr[10], pr[11]);                  \
      unsigned W0 = pk2(pr[12], pr[13]), W1 = pk2(pr[14], pr[15]);                \
      asm volatile("v_permlane32_swap_b32 %0, %1" : "+v"(Z0), "+v"(W0));          \
      asm volatile("v_permlane32_swap_b32 %0, %1" : "+v"(Z1), "+v"(W1));          \
      pa1.u[0] = Z0; pa1.u[1] = Z1; pa1.u[2] = W0; pa1.u[3] = W1;                 \
    }                                                                             \
    __builtin_amdgcn_s_setprio(1);                                                \
    {                                                                             \
      bf16x8 vf00 = *(const bf16x8*)(vb + voff[0][0]);                            \
      bf16x8 vf10 = *(const bf16x8*)(vb + voff[1][0]);                            \
      o0 = __builtin_amdgcn_mfma_f32_32x32x16_bf16(pa0.v, vf00, o0, 0, 0, 0);     \
      o1 = __builtin_amdgcn_mfma_f32_32x32x16_bf16(pa0.v, vf10, o1, 0, 0, 0);     \
      bf16x8 vf01 = *(const bf16x8*)(vb + voff[0][1]);                            \
      bf16x8 vf11 = *(const bf16x8*)(vb + voff[1][1]);                            \
      o0 = __builtin_amdgcn_mfma_f32_32x32x16_bf16(pa1.v, vf01, o0, 0, 0, 0);     \
      o1 = __builtin_amdgcn_mfma_f32_32x32x16_bf16(pa1.v, vf11, o1, 0, 0, 0);     \
    }                                                                             \
    __builtin_amdgcn_s_setprio(0);                                                \
  }

__global__ __launch_bounds__(256, 4) void attn_kernel(const u16* __restrict__ qkv,
                                                      const u16* __restrict__ vT,
                                                      u16* __restrict__ out) {
  __shared__ __align__(16) u16 Ks[4][2048];   // 4 bufs x 8 planes x 512B (K)
  __shared__ __align__(16) u16 Vs[4][2048];   // 4 bufs x 8 planes x 512B (V)
  const int tid = threadIdx.x;
  const int wave = tid >> 6, lane = tid & 63;
  const int hi = lane >> 5, l31 = lane & 31;
  const int id = blockIdx.x;
  const int bh = ((id >> 3) & 7) * 8 + (id & 7);   // XCD affinity: id%8 = bh%8
  const int b = bh >> 4, h = bh & 15;
  const int q0 = (id >> 6) * 128;
  const size_t base = (size_t)b * 2048 * 3072;
  const u16* kg = qkv + base + 1024 + h * 64;        // + t*3072 + d
  const u16* vg = vT + (size_t)bh * 64 * 2048;       // + d*2048 + t

  const int qrow = q0 + wave * 32 + l31;
  bf16x8 qf[4];
#pragma unroll
  for (int kk = 0; kk < 4; ++kk)
    qf[kk] = *(const bf16x8*)&qkv[base + (size_t)qrow * 3072 + h * 64 + kk * 16 + hi * 8];

  int koff[4];
#pragma unroll
  for (int kk = 0; kk < 4; ++kk)
    koff[kk] = (kk * 2 + hi) * 512 + l31 * 16;
  int voff[2][2];
#pragma unroll
  for (int dt = 0; dt < 2; ++dt)
#pragma unroll
    for (int kp = 0; kp < 2; ++kp)
      voff[dt][kp] = (dt * 4 + kp * 2 + hi) * 512 + l31 * 16;

  const u16* gk = kg + (size_t)l31 * 3072 + wave * 16 + hi * 8;
  const u16* gv = vg + (size_t)((wave >> 1) * 32 + l31) * 2048 + (wave & 1) * 16 + hi * 8;

  f32x16 o0 = {}, o1 = {};
  float lsum = 0.f;

  gll16((u16*)Ks[0] + wave * 512, gk); gk += 32 * 3072;
  gll16((u16*)Vs[0] + wave * 512, gv); gv += 32;
  gll16((u16*)Ks[1] + wave * 512, gk); gk += 32 * 3072;
  gll16((u16*)Vs[1] + wave * 512, gv); gv += 32;

  for (int it4 = 0; it4 < 15; ++it4) {
    ATTN_BODY(0, true, 4)
    ATTN_BODY(1, true, 4)
    ATTN_BODY(2, true, 4)
    ATTN_BODY(3, true, 4)
  }
  ATTN_BODY(0, true, 4)    // body 60: stages tile 62
  ATTN_BODY(1, true, 4)    // body 61: stages tile 63
  ATTN_BODY(2, false, 2)   // body 62
  ATTN_BODY(3, false, 0)   // body 63

  float lt = lsum + __shfl_xor(lsum, 32);
  const size_t orow0 = (size_t)b * 2048 + q0 + wave * 32;
#pragma unroll
  for (int r = 0; r < 16; ++r) {
    const int crow = (r & 3) + 8 * (r >> 2) + 4 * hi;
    const float li = __shfl(lt, crow);
    u16* orow = out + (orow0 + crow) * 1024 + h * 64 + l31;
    orow[0]  = f2bf(o0[r] / li);
    orow[32] = f2bf(o1[r] / li);
  }
}

// ---------------- launcher ----------------
extern "C" void kernel_launch(void* const* d_in, const int* in_sizes, int n_in,
                              void* d_out, int out_size, void* d_ws, size_t ws_size,
                              hipStream_t stream) {
  (void)in_sizes; (void)n_in; (void)out_size; (void)ws_size;
  const float* x     = (const float*)d_in[0];  // [4,2048,1024]
  const float* w_in  = (const float*)d_in[1];  // [1024,3072]
  const float* b_in  = (const float*)d_in[2];  // [3072]
  const float* w_out = (const float*)d_in[3];  // [1024,1024]
  const float* b_out = (const float*)d_in[4];  // [1024]
  float* out = (float*)d_out;                  // [4,2048,1024] fp32

  char* ws = (char*)d_ws;
  u16* Xbf   = (u16*)ws; ws += (size_t)8192 * 1024 * 2;  // 16.8 MB (reused as vT)
  u16* WinT  = (u16*)ws; ws += (size_t)3072 * 1024 * 2;  //  6.3 MB
  u16* WoutT = (u16*)ws; ws += (size_t)1024 * 1024 * 2;  //  2.1 MB
  u16* qkv   = (u16*)ws; ws += (size_t)8192 * 3072 * 2;  // 50.3 MB
  u16* attno = (u16*)ws;                                  // 16.8 MB (total ~92.3 MB)
  u16* vT    = Xbf;   // alias: Xbf dead after gemm1; transpose_v runs after (stream-ordered)

  pack_all<<<3072, 256, 0, stream>>>(x, w_in, w_out, Xbf, WinT, WoutT);
  gemm1_256<<<384, 512, 0, stream>>>(Xbf, WinT, b_in, qkv);
  transpose_v<<<dim3(32, 64), 256, 0, stream>>>(qkv, vT);
  attn_kernel<<<1024, 256, 0, stream>>>(qkv, vT, attno);
  gemm2_256<<<256, 512, 0, stream>>>(attno, WoutT, b_out, out);
}